// Round 9
// baseline (314.229 us; speedup 1.0000x reference)
//
#include <hip/hip_runtime.h>
#include <hip/hip_bf16.h>

#define N_NODES 50000
#define N_EDGES 600000
#define D 128

constexpr float AVG_D_LOG = 1.6094379124341003f;  // log(5)
constexpr float EPS_V = 1e-5f;

// ---- workspace byte offsets (total ~93.1 MB)
#define PQ_B     0ul           // bf16 [50000][256]  P|Q rows     = 25,600,000
#define AGG_B    25600000ul    // bf16 [50000][512]  mean|max|min|std = 51,200,000
#define HBF_B    76800000ul    // bf16 [50000][128]
#define WPRET2_B 89600000ul    // bf16 [256][128]   (P cols | Q cols, [n][k])
#define WPOSTT_B 89665536ul    // bf16 [128][1664]
#define WMIXT_B  90091520ul    // bf16 [128][128]
#define DEGC_B   90124288ul    // int  [50000]
#define OFF_B    90324288ul    // int  [50016]
#define CUR_B    90524352ul    // int  [50000]
#define SRCS_B   90724352ul    // int  [600000]  src ids in dst-sorted order
#define GCNT_B   93124352ul    // int  [1]  global range allocator

typedef __attribute__((ext_vector_type(8))) short bf16x8;
typedef __attribute__((ext_vector_type(4))) float f32x4;

__device__ __forceinline__ short f2b(float f) {
    unsigned u = __builtin_bit_cast(unsigned, f);
    u += 0x7fffu + ((u >> 16) & 1u);   // RNE
    return (short)(u >> 16);
}
__device__ __forceinline__ unsigned pk2(float a, float b) {
    return (unsigned)(unsigned short)f2b(a) | ((unsigned)(unsigned short)f2b(b) << 16);
}
__device__ __forceinline__ float blo(unsigned u) { return __uint_as_float(u << 16); }
__device__ __forceinline__ float bhi(unsigned u) { return __uint_as_float(u & 0xffff0000u); }

// async global->LDS, 16B per lane; LDS dest = wave-uniform base + lane*16
__device__ __forceinline__ void gld_lds16(const void* g, void* l) {
    __builtin_amdgcn_global_load_lds(
        (const __attribute__((address_space(1))) void*)g,
        (__attribute__((address_space(3))) void*)l, 16, 0, 0);
}

// counted-vmcnt barrier pair (T4)
#define WAIT_BAR(N) do {                                              \
    asm volatile("s_waitcnt vmcnt(" #N ")" ::: "memory");             \
    __builtin_amdgcn_sched_barrier(0);                                \
    __builtin_amdgcn_s_barrier();                                     \
    __builtin_amdgcn_sched_barrier(0);                                \
} while (0)
#define BAR_ONLY() do {                                               \
    __builtin_amdgcn_sched_barrier(0);                                \
    __builtin_amdgcn_s_barrier();                                     \
    __builtin_amdgcn_sched_barrier(0);                                \
} while (0)
#define SB0() __builtin_amdgcn_sched_barrier(0)
#define LGKM0() do { asm volatile("s_waitcnt lgkmcnt(0)" ::: "memory"); SB0(); } while (0)

// ---------------------------------------------------------------- prep (+ fused edge histogram)
// degc/cursor/gcnt are zeroed by hipMemsetAsync before this launch.
__global__ __launch_bounds__(256) void prep_kernel(
    const float* __restrict__ h, const float* __restrict__ Wpre,
    const float* __restrict__ Wpost, const float* __restrict__ Wmix,
    const int* __restrict__ edst,
    short* __restrict__ hbf, short* __restrict__ wpreT2,
    short* __restrict__ wpostT, short* __restrict__ wmixT,
    int* __restrict__ degc)
{
    long i = (long)blockIdx.x * 256 + threadIdx.x;
    if (i < 800000) {   // 6.4M elements, 8 per thread
        float4 a = *(const float4*)(h + i * 8);
        float4 b = *(const float4*)(h + i * 8 + 4);
        int4 v;
        v.x = (int)pk2(a.x, a.y); v.y = (int)pk2(a.z, a.w);
        v.z = (int)pk2(b.x, b.y); v.w = (int)pk2(b.z, b.w);
        *(int4*)(hbf + i * 8) = v;
        return;
    }
    i -= 800000;
    if (i < 32768) {  // wpreT2[n][k]: n<128 -> Wpre[k][n] (top); n>=128 -> Wpre[k+128][n-128]
        int n = i >> 7, k = i & 127;
        float v = (n < 128) ? Wpre[k * 128 + n] : Wpre[(k + 128) * 128 + (n - 128)];
        wpreT2[n * 128 + k] = f2b(v);
        return;
    }
    i -= 32768;
    if (i < 212992) { int k = i >> 7, n = i & 127; wpostT[n * 1664 + k] = f2b(Wpost[k * 128 + n]); return; }
    i -= 212992;
    if (i < 16384) { int k = i >> 7, n = i & 127; wmixT[n * 128 + k] = f2b(Wmix[k * 128 + n]); return; }
    i -= 16384;
    if (i < N_EDGES) atomicAdd(&degc[edst[i]], 1);   // fused histogram
}
#define PREP_BLOCKS ((800000 + 32768 + 212992 + 16384 + N_EDGES + 255) / 256)

// ---------------------------------------------------------------- range alloc (replaces 3-kernel scan)
__global__ __launch_bounds__(256) void alloc_kernel(const int* __restrict__ degc,
                                                    int* __restrict__ off, int* __restrict__ gcnt) {
    int n = blockIdx.x * 256 + threadIdx.x;
    int d = (n < N_NODES) ? degc[n] : 0;
    int pre = d;
#pragma unroll
    for (int o = 1; o < 64; o <<= 1) {
        int t = __shfl_up(pre, o);
        if ((threadIdx.x & 63) >= o) pre += t;
    }
    int base = 0;
    if ((threadIdx.x & 63) == 63) base = atomicAdd(gcnt, pre);   // pre = wave total at lane 63
    base = __shfl(base, 63);
    if (n < N_NODES) off[n] = base + pre - d;                    // exclusive within wave
}

// ---------------------------------------------------------------- scatter srcs into dst-sorted order
__global__ __launch_bounds__(256) void scatter_kernel(const int* __restrict__ esrc, const int* __restrict__ edst,
                                                      const int* __restrict__ off, int* __restrict__ cursor,
                                                      int* __restrict__ srcs) {
    int e = blockIdx.x * 256 + threadIdx.x;
    if (e < N_EDGES) {
        int d = edst[e];
        int p = off[d] + atomicAdd(&cursor[d], 1);
        srcs[p] = esrc[e];
    }
}

// ---------------------------------------------------------------- shared GEMM stage/compute helpers
// stage one 128x64 A tile (node rows): 4 gld_lds per wave (256-thread block)
__device__ __forceinline__ void stageA_t(short* ldsT, const short* src, int rs, int co,
                                         int bn, int wv, int lane) {
    const int sub = lane >> 3, seg = lane & 7;
    const int sg = (seg ^ sub) * 8;          // pre-swizzled global seg (row&7 == sub)
#pragma unroll
    for (int t = 0; t < 4; t++) {
        int i = wv * 4 + t;
        int row = i * 8 + sub;
        int n = bn + row; if (n >= N_NODES) n = N_NODES - 1;
        gld_lds16(src + (long)n * rs + co + sg, ldsT + i * 512);
    }
}
// stage one 128x64 B tile (weight rows, no clamp)
__device__ __forceinline__ void stageB_t(short* ldsT, const short* src, int rs, int co,
                                         int wv, int lane) {
    const int sub = lane >> 3, seg = lane & 7;
    const int sg = (seg ^ sub) * 8;
#pragma unroll
    for (int t = 0; t < 4; t++) {
        int i = wv * 4 + t;
        int row = i * 8 + sub;
        gld_lds16(src + (long)row * rs + co + sg, ldsT + i * 512);
    }
}
// load 4 A-fragments (rt x ks) for this wave's 32 rows, K=64 chunk at co, direct global->reg
__device__ __forceinline__ void loadAfr(bf16x8* a, const short* src, int rs, int co,
                                        int bn, int wv, int lm, int quad) {
#pragma unroll
    for (int rt = 0; rt < 2; rt++)
#pragma unroll
        for (int ks = 0; ks < 2; ks++) {
            int n = bn + wv * 32 + rt * 16 + lm; if (n >= N_NODES) n = N_NODES - 1;
            a[rt * 2 + ks] = *(const bf16x8*)(src + (long)n * rs + co + ks * 32 + quad * 8);
        }
}

// MFMA group, A from LDS
#define MFMA_ITER(AB, BB, ACC)                                                      \
    {                                                                               \
        _Pragma("unroll")                                                           \
        for (int ks = 0; ks < 2; ks++) {                                            \
            const int qx = (((ks * 4 + quad) ^ r7) * 8);                            \
            bf16x8 a0 = *(const bf16x8*)&(AB)[(wv * 32 + lm) * 64 + qx];            \
            bf16x8 a1 = *(const bf16x8*)&(AB)[(wv * 32 + 16 + lm) * 64 + qx];       \
            _Pragma("unroll")                                                       \
            for (int ct = 0; ct < 8; ct++) {                                        \
                bf16x8 b = *(const bf16x8*)&(BB)[(ct * 16 + lm) * 64 + qx];         \
                ACC[0][ct] = __builtin_amdgcn_mfma_f32_16x16x32_bf16(b, a0, ACC[0][ct], 0, 0, 0); \
                ACC[1][ct] = __builtin_amdgcn_mfma_f32_16x16x32_bf16(b, a1, ACC[1][ct], 0, 0, 0); \
            }                                                                       \
        }                                                                           \
    }

// MFMA group, A from registers (AF = bf16x8[4]: rt0ks0,rt0ks1,rt1ks0,rt1ks1)
#define MFMA_RG(BB, AF, ACC, FRESH)                                                 \
    {                                                                               \
        __builtin_amdgcn_s_setprio(1);                                              \
        _Pragma("unroll")                                                           \
        for (int ks = 0; ks < 2; ks++) {                                            \
            const int qx = ((ks * 4 + quad) ^ r7) * 8;                              \
            _Pragma("unroll")                                                       \
            for (int ct = 0; ct < 8; ct++) {                                        \
                bf16x8 b = *(const bf16x8*)&(BB)[(ct * 16 + lm) * 64 + qx];         \
                f32x4 c0 = ((FRESH) && ks == 0) ? (f32x4){0.f, 0.f, 0.f, 0.f} : ACC[0][ct]; \
                f32x4 c1 = ((FRESH) && ks == 0) ? (f32x4){0.f, 0.f, 0.f, 0.f} : ACC[1][ct]; \
                ACC[0][ct] = __builtin_amdgcn_mfma_f32_16x16x32_bf16(b, (AF)[ks], c0, 0, 0, 0); \
                ACC[1][ct] = __builtin_amdgcn_mfma_f32_16x16x32_bf16(b, (AF)[2 + ks], c1, 0, 0, 0); \
            }                                                                       \
        }                                                                           \
        __builtin_amdgcn_s_setprio(0);                                              \
    }

#define FOLD(SRC, S0, S1)                                                           \
    _Pragma("unroll")                                                               \
    for (int ct = 0; ct < 8; ct++) {                                                \
        mI[0][ct] += (S0) * SRC[0][ct];                                             \
        mI[1][ct] += (S1) * SRC[1][ct];                                             \
    }

// ---------------------------------------------------------------- PQ = h @ [Wtop | Wbot] (+bias on Q)
__global__ __launch_bounds__(256, 2) void gemm_pq_kernel(
    const short* __restrict__ hbf, const short* __restrict__ wpreT2,
    const float* __restrict__ bpre, short* __restrict__ PQ)
{
    __shared__ __align__(16) short As[2][8192];
    __shared__ __align__(16) short Bs[2][8192];

    const int tid = threadIdx.x;
    const int cg = blockIdx.x & 1;            // 0 = P cols, 1 = Q cols
    const int bn = (blockIdx.x >> 1) * 128;
    const int lane = tid & 63, wv = tid >> 6;
    const int lm = lane & 15, quad = lane >> 4;
    const int r7 = lm & 7;
    const short* Bsrc = wpreT2 + cg * 128 * 128;   // this block's 128 weight rows, [n][k=128]

    f32x4 acc[2][8];
#pragma unroll
    for (int a = 0; a < 2; a++)
#pragma unroll
        for (int b = 0; b < 8; b++) acc[a][b] = (f32x4){0.f, 0.f, 0.f, 0.f};

    // issue k0 (8) then k1 (8) -> 16 in flight
    stageA_t(As[0], hbf, 128, 0, bn, wv, lane);
    stageB_t(Bs[0], Bsrc, 128, 0, wv, lane);
    stageA_t(As[1], hbf, 128, 64, bn, wv, lane);
    stageB_t(Bs[1], Bsrc, 128, 64, wv, lane);
    WAIT_BAR(8);                       // k0 landed (all waves)
    MFMA_ITER(As[0], Bs[0], acc);
    WAIT_BAR(0);                       // k1 landed
    MFMA_ITER(As[1], Bs[1], acc);

#pragma unroll
    for (int rt = 0; rt < 2; rt++) {
        int row = wv * 32 + rt * 16 + lm;
        int n = bn + row;
        if (n >= N_NODES) continue;
        short* dst = PQ + (long)n * 256;
#pragma unroll
        for (int ct = 0; ct < 8; ct++) {
            int col = cg * 128 + ct * 16 + quad * 4;
            float v0 = acc[rt][ct][0], v1 = acc[rt][ct][1], v2 = acc[rt][ct][2], v3 = acc[rt][ct][3];
            if (cg) {
                float4 bv = *(const float4*)(bpre + (col - 128));
                v0 += bv.x; v1 += bv.y; v2 += bv.z; v3 += bv.w;
            }
            int2 pkd; pkd.x = (int)pk2(v0, v1); pkd.y = (int)pk2(v2, v3);
            *(int2*)(dst + col) = pkd;
        }
    }
}

// ---------------------------------------------------------------- fused edge compute + stats: one wave per node
__global__ __launch_bounds__(256) void edgestats_kernel(
    const short* __restrict__ PQ, const int* __restrict__ srcs,
    const int* __restrict__ off, const int* __restrict__ degc, short* __restrict__ aggbf)
{
    const int wv = threadIdx.x >> 6, lane = threadIdx.x & 63;
    const int n = blockIdx.x * 4 + wv;            // grid 12500 * 4 waves = 50000
    const unsigned* Pb = (const unsigned*)PQ;     // u32 view: row = 128 u32 (P=0..63, Q=64..127)

    const int s0 = __builtin_amdgcn_readfirstlane(off[n]);
    const int s1 = s0 + __builtin_amdgcn_readfirstlane(degc[n]);

    unsigned qu = Pb[(long)n * 128 + 64 + lane];
    const float qa = blo(qu), qb = bhi(qu);

    float sA = 0.f, sB = 0.f, qA = 0.f, qB = 0.f;
    float mxA = -1e30f, mxB = -1e30f, mnA = 1e30f, mnB = 1e30f;

    int p = s0;
    for (; p + 8 <= s1; p += 8) {
        int idx[8];
#pragma unroll
        for (int j = 0; j < 8; j++) idx[j] = srcs[p + j];
        unsigned u[8];
#pragma unroll
        for (int j = 0; j < 8; j++) u[j] = Pb[(long)idx[j] * 128 + lane];
#pragma unroll
        for (int j = 0; j < 8; j++) {
            float a = blo(u[j]) + qa; a = a > 0.f ? a : 0.f;
            float b = bhi(u[j]) + qb; b = b > 0.f ? b : 0.f;
            sA += a; sB += b; qA += a * a; qB += b * b;
            mxA = fmaxf(mxA, a); mxB = fmaxf(mxB, b);
            mnA = fminf(mnA, a); mnB = fminf(mnB, b);
        }
    }
    if (p + 4 <= s1) {
        int idx[4];
#pragma unroll
        for (int j = 0; j < 4; j++) idx[j] = srcs[p + j];
        unsigned u[4];
#pragma unroll
        for (int j = 0; j < 4; j++) u[j] = Pb[(long)idx[j] * 128 + lane];
#pragma unroll
        for (int j = 0; j < 4; j++) {
            float a = blo(u[j]) + qa; a = a > 0.f ? a : 0.f;
            float b = bhi(u[j]) + qb; b = b > 0.f ? b : 0.f;
            sA += a; sB += b; qA += a * a; qB += b * b;
            mxA = fmaxf(mxA, a); mxB = fmaxf(mxB, b);
            mnA = fminf(mnA, a); mnB = fminf(mnB, b);
        }
        p += 4;
    }
    for (; p < s1; p++) {
        unsigned u = Pb[(long)srcs[p] * 128 + lane];
        float a = blo(u) + qa; a = a > 0.f ? a : 0.f;
        float b = bhi(u) + qb; b = b > 0.f ? b : 0.f;
        sA += a; sB += b; qA += a * a; qB += b * b;
        mxA = fmaxf(mxA, a); mxB = fmaxf(mxB, b);
        mnA = fminf(mnA, a); mnB = fminf(mnB, b);
    }

    float inv = 1.0f / (float)(s1 - s0);   // deg >= 1 guaranteed (self-loops)
    float mA = sA * inv, mB = sB * inv;
    float vA = qA * inv - mA * mA; vA = vA > 0.f ? vA : 0.f;
    float vB = qB * inv - mB * mB; vB = vB > 0.f ? vB : 0.f;
    float stA = sqrtf(vA + EPS_V), stB = sqrtf(vB + EPS_V);

    unsigned* ag = (unsigned*)(aggbf + (long)n * 512);
    ag[lane]       = pk2(mA, mB);
    ag[64 + lane]  = pk2(mxA, mxB);
    ag[128 + lane] = pk2(mnA, mnB);
    ag[192 + lane] = pk2(stA, stB);
}

// ---------------------------------------------------------------- fused post + mix per node
// v8: v7 schedule with A fully register-resident in the j-loop (each wave only ever
// reads its own 32 rows -> LDS round trip was waste). LDS 65->49 KB => 3 blocks/CU,
// all 391 blocks co-resident. Same WAIT_BAR(0)/(0)/(4) ledger as v7; SB0 pins
// gld_lds-before-reg-load issue order (vmcnt counts both). Mix hp staging is
// wave-private -> single 16KB buffer, no cross-wave barriers between mix chunks.
__global__ __launch_bounds__(256, 3) void node_kernel(
    const float* __restrict__ h, const short* __restrict__ hbf, const short* __restrict__ aggbf,
    const int* __restrict__ degc, const short* __restrict__ wpostT, const float* __restrict__ bpost,
    const short* __restrict__ wmixT, const float* __restrict__ bmix, float* __restrict__ out)
{
    __shared__ __align__(16) short Bs[2][8192];   // 32 KB weight double-buffer
    __shared__ __align__(16) short hpS[8192];     // 16 KB hp staging (wave-private rows)
    __shared__ float sAmp[128], sAtt[128];

    const int tid = threadIdx.x;
    const int bn = blockIdx.x * 128;
    const int lane = tid & 63, wv = tid >> 6;
    const int lm = lane & 15, quad = lane >> 4;
    const int r7 = lm & 7;

    if (tid < 128) {
        int n = bn + tid; if (n >= N_NODES) n = N_NODES - 1;
        float d = (float)degc[n];
        float ld = logf(d + 1.0f);
        sAmp[tid] = ld * (1.0f / AVG_D_LOG);
        sAtt[tid] = AVG_D_LOG / ld;
    }
    __syncthreads();   // drains degc load -> vmcnt baseline 0 for exact counted waits

    const float am0 = sAmp[wv * 32 + lm],      at0 = sAtt[wv * 32 + lm];
    const float am1 = sAmp[wv * 32 + 16 + lm], at1 = sAtt[wv * 32 + 16 + lm];

    f32x4 mI[2][8];              // master accumulator (FRESH at P0)
    bf16x8 aCur[4], aNxt[4];     // agg A-frag double buffer (static names)

    // prologue: Bc0 (4 lds) first, then 12 reg loads (hA0, hA1, aCur=agg0)
    bf16x8 hA0[4], hA1[4];
    stageB_t(Bs[0], wpostT, 1664, 0, wv, lane);
    SB0();
    loadAfr(hA0, hbf, 128, 0, bn, wv, lm, quad);
    loadAfr(hA1, hbf, 128, 64, bn, wv, lm, quad);
    loadAfr(aCur, aggbf, 512, 0, bn, wv, lm, quad);

    // P0: wait Bc0 (12 newest = reg loads, compiler auto-waits hA0 regs); stage Bc1; MFMA h0 x c0
    WAIT_BAR(12);
    stageB_t(Bs[1], wpostT, 1664, 64, wv, lane);
    MFMA_RG(Bs[0], hA0, mI, 1);

    // P1: drain (Bc1 + stragglers); stage Bid0 -> Bs[0]; MFMA h1 x c1
    WAIT_BAR(0);
    stageB_t(Bs[0], wpostT, 1664, 2 * 64, wv, lane);
    MFMA_RG(Bs[1], hA1, mI, 0);

    // j-loop unrolled by 2 for static aCur/aNxt. id_j lives in Bs[j&1].
    for (int jp = 0; jp < 4; jp++) {
        const int j0 = 2 * jp, j1 = 2 * jp + 1;

        // ---- j0 (even): s0 id
        WAIT_BAR(0);
        stageB_t(Bs[1], wpostT, 1664, (10 + j0) * 64, wv, lane);      // amp_j0
        MFMA_RG(Bs[0], aCur, mI, 0);
        // s1 amp
        WAIT_BAR(0);
        stageB_t(Bs[0], wpostT, 1664, (18 + j0) * 64, wv, lane);      // att_j0
        SB0();
        loadAfr(aNxt, aggbf, 512, (j0 >> 1) * 128 + 64, bn, wv, lm, quad);  // agg j0+1 (odd)
        {
            f32x4 tp[2][8];
            MFMA_RG(Bs[1], aCur, tp, 1);
            FOLD(tp, am0, am1);
        }
        // s2 att
        WAIT_BAR(4);                                                  // att landed, aNxt in flight
        stageB_t(Bs[1], wpostT, 1664, (3 + j0) * 64, wv, lane);       // id_{j0+1}
        {
            f32x4 tp[2][8];
            MFMA_RG(Bs[0], aCur, tp, 1);
            FOLD(tp, at0, at1);
        }

        // ---- j1 (odd): s0 id
        WAIT_BAR(0);
        stageB_t(Bs[0], wpostT, 1664, (10 + j1) * 64, wv, lane);      // amp_j1
        MFMA_RG(Bs[1], aNxt, mI, 0);
        // s1 amp
        WAIT_BAR(0);
        stageB_t(Bs[1], wpostT, 1664, (18 + j1) * 64, wv, lane);      // att_j1
        if (j1 < 7) {
            SB0();
            loadAfr(aCur, aggbf, 512, ((j1 + 1) >> 1) * 128, bn, wv, lm, quad);  // agg j1+1 (even)
        }
        {
            f32x4 tp[2][8];
            MFMA_RG(Bs[0], aNxt, tp, 1);
            FOLD(tp, am0, am1);
        }
        // s2 att
        if (j1 < 7) { WAIT_BAR(4); } else { WAIT_BAR(0); }
        if (j1 < 7) stageB_t(Bs[0], wpostT, 1664, (3 + j1) * 64, wv, lane);   // id_{j1+1}
        else        stageB_t(Bs[0], wmixT, 128, 0, wv, lane);                  // Bmix0 -> Bs[0]
        {
            f32x4 tp[2][8];
            MFMA_RG(Bs[1], aNxt, tp, 1);
            FOLD(tp, at0, at1);
        }
    }
    // Bmix0 in flight -> Bs[0]

    // tail: protect Bs[1] (att7 reads done at barrier), stage Bmix1 -> Bs[1]
    BAR_ONLY();
    stageB_t(Bs[1], wmixT, 128, 64, wv, lane);

    // hp = relu(mI + bpost) in place
#pragma unroll
    for (int rt = 0; rt < 2; rt++)
#pragma unroll
        for (int ct = 0; ct < 8; ct++) {
            float4 bv = *(const float4*)(bpost + ct * 16 + quad * 4);
            mI[rt][ct][0] = fmaxf(mI[rt][ct][0] + bv.x, 0.f);
            mI[rt][ct][1] = fmaxf(mI[rt][ct][1] + bv.y, 0.f);
            mI[rt][ct][2] = fmaxf(mI[rt][ct][2] + bv.z, 0.f);
            mI[rt][ct][3] = fmaxf(mI[rt][ct][3] + bv.w, 0.f);
        }

    // mix kc=0: write hp cols 0-63 (swizzled) -> hpS (own rows only)
#pragma unroll
    for (int rt = 0; rt < 2; rt++) {
        const int row = wv * 32 + rt * 16 + lm;
#pragma unroll
        for (int ct = 0; ct < 4; ct++) {
            int2 pkd; pkd.x = (int)pk2(mI[rt][ct][0], mI[rt][ct][1]);
            pkd.y = (int)pk2(mI[rt][ct][2], mI[rt][ct][3]);
            const int cb = ct * 32 + quad * 8;
            const int sb = ((((cb >> 4) ^ r7) << 4) | (cb & 15));
            *(int2*)((char*)hpS + row * 128 + sb) = pkd;
        }
    }
    __syncthreads();   // full drain: Bmix vmcnt + hp lgkm; all waves' B stages visible

    f32x4 accO[2][8];
#pragma unroll
    for (int a = 0; a < 2; a++)
#pragma unroll
        for (int b = 0; b < 8; b++) accO[a][b] = (f32x4){0.f, 0.f, 0.f, 0.f};
    MFMA_ITER(hpS, Bs[0], accO);

    // mix kc=1: hpS rows are wave-private; order reads->writes->reads via lgkm
    LGKM0();
#pragma unroll
    for (int rt = 0; rt < 2; rt++) {
        const int row = wv * 32 + rt * 16 + lm;
#pragma unroll
        for (int ct = 4; ct < 8; ct++) {
            int2 pkd; pkd.x = (int)pk2(mI[rt][ct][0], mI[rt][ct][1]);
            pkd.y = (int)pk2(mI[rt][ct][2], mI[rt][ct][3]);
            const int cb = (ct - 4) * 32 + quad * 8;
            const int sb = ((((cb >> 4) ^ r7) << 4) | (cb & 15));
            *(int2*)((char*)hpS + row * 128 + sb) = pkd;
        }
    }
    LGKM0();
    MFMA_ITER(hpS, Bs[1], accO);

    // epilogue: out = h + leaky_relu(accO + b_mix)
#pragma unroll
    for (int rt = 0; rt < 2; rt++) {
        int row = wv * 32 + rt * 16 + lm;
        int n = bn + row;
        if (n >= N_NODES) continue;
#pragma unroll
        for (int ct = 0; ct < 8; ct++) {
            int col = ct * 16 + quad * 4;
            float4 bv = *(const float4*)(bmix + col);
            float4 hv = *(const float4*)(h + (long)n * 128 + col);
            float4 o;
            float v0 = accO[rt][ct][0] + bv.x; v0 = v0 > 0.f ? v0 : 0.01f * v0; o.x = hv.x + v0;
            float v1 = accO[rt][ct][1] + bv.y; v1 = v1 > 0.f ? v1 : 0.01f * v1; o.y = hv.y + v1;
            float v2 = accO[rt][ct][2] + bv.z; v2 = v2 > 0.f ? v2 : 0.01f * v2; o.z = hv.z + v2;
            float v3 = accO[rt][ct][3] + bv.w; v3 = v3 > 0.f ? v3 : 0.01f * v3; o.w = hv.w + v3;
            *(float4*)(out + (long)n * 128 + col) = o;
        }
    }
}

extern "C" void kernel_launch(void* const* d_in, const int* in_sizes, int n_in,
                              void* d_out, int out_size, void* d_ws, size_t ws_size,
                              hipStream_t stream) {
    const float* h     = (const float*)d_in[0];
    const int*   esrc  = (const int*)d_in[1];
    const int*   edst  = (const int*)d_in[2];
    const float* Wpre  = (const float*)d_in[3];
    const float* bpre  = (const float*)d_in[4];
    const float* Wpost = (const float*)d_in[5];
    const float* bpost = (const float*)d_in[6];
    const float* Wmix  = (const float*)d_in[7];
    const float* bmix  = (const float*)d_in[8];
    float* out = (float*)d_out;
    char* ws = (char*)d_ws;

    short* PQ     = (short*)(ws + PQ_B);
    short* aggbf  = (short*)(ws + AGG_B);
    short* hbf    = (short*)(ws + HBF_B);
    short* wpreT2 = (short*)(ws + WPRET2_B);
    short* wpostT = (short*)(ws + WPOSTT_B);
    short* wmixT  = (short*)(ws + WMIXT_B);
    int*   degc   = (int*)(ws + DEGC_B);
    int*   off    = (int*)(ws + OFF_B);
    int*   cursor = (int*)(ws + CUR_B);
    int*   srcs   = (int*)(ws + SRCS_B);
    int*   gcnt   = (int*)(ws + GCNT_B);

    hipMemsetAsync(ws + DEGC_B, 0, N_NODES * 4, stream);   // degc = 0
    hipMemsetAsync(ws + CUR_B,  0, N_NODES * 4, stream);   // cursor = 0
    hipMemsetAsync(ws + GCNT_B, 0, 4, stream);             // gcnt = 0
    prep_kernel<<<PREP_BLOCKS, 256, 0, stream>>>(h, Wpre, Wpost, Wmix, edst, hbf, wpreT2, wpostT, wmixT, degc);
    alloc_kernel<<<(N_NODES + 255) / 256, 256, 0, stream>>>(degc, off, gcnt);
    scatter_kernel<<<(N_EDGES + 255) / 256, 256, 0, stream>>>(esrc, edst, off, cursor, srcs);
    gemm_pq_kernel<<<((N_NODES + 127) / 128) * 2, 256, 0, stream>>>(hbf, wpreT2, bpre, PQ);
    edgestats_kernel<<<N_NODES / 4, 256, 0, stream>>>(PQ, srcs, off, degc, aggbf);
    node_kernel<<<(N_NODES + 127) / 128, 256, 0, stream>>>(h, hbf, aggbf, degc, wpostT, bpost, wmixT, bmix, out);
}

// Round 10
// 291.644 us; speedup vs baseline: 1.0774x; 1.0774x over previous
//
#include <hip/hip_runtime.h>
#include <hip/hip_bf16.h>

#define N_NODES 50000
#define N_EDGES 600000
#define D 128

constexpr float AVG_D_LOG = 1.6094379124341003f;  // log(5)
constexpr float EPS_V = 1e-5f;

// ---- workspace byte offsets (total ~93.1 MB)
#define PQ_B     0ul           // bf16 [50000][256]  P|Q rows     = 25,600,000
#define AGG_B    25600000ul    // bf16 [50000][512]  mean|max|min|std = 51,200,000
#define HBF_B    76800000ul    // bf16 [50000][128]
#define WPRET2_B 89600000ul    // bf16 [256][128]   (P cols | Q cols, [n][k])
#define WPOSTT_B 89665536ul    // bf16 [128][1664]
#define WMIXT_B  90091520ul    // bf16 [128][128]
#define DEGC_B   90124288ul    // int  [50000]
#define OFF_B    90324288ul    // int  [50016]
#define CUR_B    90524352ul    // int  [50000]
#define SRCS_B   90724352ul    // int  [600000]  src ids in dst-sorted order
#define GCNT_B   93124352ul    // int  [1]  global range allocator

typedef __attribute__((ext_vector_type(8))) short bf16x8;
typedef __attribute__((ext_vector_type(4))) float f32x4;

__device__ __forceinline__ short f2b(float f) {
    unsigned u = __builtin_bit_cast(unsigned, f);
    u += 0x7fffu + ((u >> 16) & 1u);   // RNE
    return (short)(u >> 16);
}
__device__ __forceinline__ unsigned pk2(float a, float b) {
    return (unsigned)(unsigned short)f2b(a) | ((unsigned)(unsigned short)f2b(b) << 16);
}
__device__ __forceinline__ float blo(unsigned u) { return __uint_as_float(u << 16); }
__device__ __forceinline__ float bhi(unsigned u) { return __uint_as_float(u & 0xffff0000u); }

// async global->LDS, 16B per lane; LDS dest = wave-uniform base + lane*16
__device__ __forceinline__ void gld_lds16(const void* g, void* l) {
    __builtin_amdgcn_global_load_lds(
        (const __attribute__((address_space(1))) void*)g,
        (__attribute__((address_space(3))) void*)l, 16, 0, 0);
}

// counted-vmcnt barrier pair (T4)
#define WAIT_BAR(N) do {                                              \
    asm volatile("s_waitcnt vmcnt(" #N ")" ::: "memory");             \
    __builtin_amdgcn_sched_barrier(0);                                \
    __builtin_amdgcn_s_barrier();                                     \
    __builtin_amdgcn_sched_barrier(0);                                \
} while (0)
#define BAR_ONLY() do {                                               \
    __builtin_amdgcn_sched_barrier(0);                                \
    __builtin_amdgcn_s_barrier();                                     \
    __builtin_amdgcn_sched_barrier(0);                                \
} while (0)
#define SB0() __builtin_amdgcn_sched_barrier(0)
#define LGKM0() do { asm volatile("s_waitcnt lgkmcnt(0)" ::: "memory"); SB0(); } while (0)

// ---------------------------------------------------------------- prep (8-wide vectorized h conversion)
__global__ __launch_bounds__(256) void prep_kernel(
    const float* __restrict__ h, const float* __restrict__ Wpre,
    const float* __restrict__ Wpost, const float* __restrict__ Wmix,
    short* __restrict__ hbf, short* __restrict__ wpreT2,
    short* __restrict__ wpostT, short* __restrict__ wmixT,
    int* __restrict__ degc, int* __restrict__ cursor, int* __restrict__ gcnt)
{
    long i = (long)blockIdx.x * 256 + threadIdx.x;
    if (i < 800000) {   // 6.4M elements, 8 per thread
        float4 a = *(const float4*)(h + i * 8);
        float4 b = *(const float4*)(h + i * 8 + 4);
        int4 v;
        v.x = (int)pk2(a.x, a.y); v.y = (int)pk2(a.z, a.w);
        v.z = (int)pk2(b.x, b.y); v.w = (int)pk2(b.z, b.w);
        *(int4*)(hbf + i * 8) = v;
        return;
    }
    i -= 800000;
    if (i < 32768) {  // wpreT2[n][k]: n<128 -> Wpre[k][n] (top); n>=128 -> Wpre[k+128][n-128]
        int n = i >> 7, k = i & 127;
        float v = (n < 128) ? Wpre[k * 128 + n] : Wpre[(k + 128) * 128 + (n - 128)];
        wpreT2[n * 128 + k] = f2b(v);
        return;
    }
    i -= 32768;
    if (i < 212992) { int k = i >> 7, n = i & 127; wpostT[n * 1664 + k] = f2b(Wpost[k * 128 + n]); return; }
    i -= 212992;
    if (i < 16384) { int k = i >> 7, n = i & 127; wmixT[n * 128 + k] = f2b(Wmix[k * 128 + n]); return; }
    i -= 16384;
    if (i < N_NODES) { degc[i] = 0; return; }
    i -= N_NODES;
    if (i < N_NODES) { cursor[i] = 0; return; }
    i -= N_NODES;
    if (i == 0) *gcnt = 0;
}
#define PREP_BLOCKS ((800000 + 32768 + 212992 + 16384 + 2 * N_NODES + 1 + 255) / 256)

// ---------------------------------------------------------------- degree histogram
__global__ __launch_bounds__(256) void hist_kernel(const int* __restrict__ edst, int* __restrict__ degc) {
    int e = blockIdx.x * 256 + threadIdx.x;
    if (e < N_EDGES) atomicAdd(&degc[edst[e]], 1);
}

// ---------------------------------------------------------------- range alloc (replaces 3-kernel scan)
__global__ __launch_bounds__(256) void alloc_kernel(const int* __restrict__ degc,
                                                    int* __restrict__ off, int* __restrict__ gcnt) {
    int n = blockIdx.x * 256 + threadIdx.x;
    int d = (n < N_NODES) ? degc[n] : 0;
    int pre = d;
#pragma unroll
    for (int o = 1; o < 64; o <<= 1) {
        int t = __shfl_up(pre, o);
        if ((threadIdx.x & 63) >= o) pre += t;
    }
    int base = 0;
    if ((threadIdx.x & 63) == 63) base = atomicAdd(gcnt, pre);   // pre = wave total at lane 63
    base = __shfl(base, 63);
    if (n < N_NODES) off[n] = base + pre - d;                    // exclusive within wave
}

// ---------------------------------------------------------------- scatter srcs into dst-sorted order
__global__ __launch_bounds__(256) void scatter_kernel(const int* __restrict__ esrc, const int* __restrict__ edst,
                                                      const int* __restrict__ off, int* __restrict__ cursor,
                                                      int* __restrict__ srcs) {
    int e = blockIdx.x * 256 + threadIdx.x;
    if (e < N_EDGES) {
        int d = edst[e];
        int p = off[d] + atomicAdd(&cursor[d], 1);
        srcs[p] = esrc[e];
    }
}

// ---------------------------------------------------------------- shared GEMM stage/compute helpers
// stage one 128x64 A tile (node rows): 4 gld_lds per wave (256-thread block)
__device__ __forceinline__ void stageA_t(short* ldsT, const short* src, int rs, int co,
                                         int bn, int wv, int lane) {
    const int sub = lane >> 3, seg = lane & 7;
    const int sg = (seg ^ sub) * 8;          // pre-swizzled global seg (row&7 == sub)
#pragma unroll
    for (int t = 0; t < 4; t++) {
        int i = wv * 4 + t;
        int row = i * 8 + sub;
        int n = bn + row; if (n >= N_NODES) n = N_NODES - 1;
        gld_lds16(src + (long)n * rs + co + sg, ldsT + i * 512);
    }
}
// stage one 128x64 B tile (weight rows, no clamp)
__device__ __forceinline__ void stageB_t(short* ldsT, const short* src, int rs, int co,
                                         int wv, int lane) {
    const int sub = lane >> 3, seg = lane & 7;
    const int sg = (seg ^ sub) * 8;
#pragma unroll
    for (int t = 0; t < 4; t++) {
        int i = wv * 4 + t;
        int row = i * 8 + sub;
        gld_lds16(src + (long)row * rs + co + sg, ldsT + i * 512);
    }
}
// load 4 A-fragments (rt x ks) for this wave's 32 rows, K=64 chunk at co, direct global->reg
__device__ __forceinline__ void loadAfr(bf16x8* a, const short* src, int rs, int co,
                                        int bn, int wv, int lm, int quad) {
#pragma unroll
    for (int rt = 0; rt < 2; rt++)
#pragma unroll
        for (int ks = 0; ks < 2; ks++) {
            int n = bn + wv * 32 + rt * 16 + lm; if (n >= N_NODES) n = N_NODES - 1;
            a[rt * 2 + ks] = *(const bf16x8*)(src + (long)n * rs + co + ks * 32 + quad * 8);
        }
}

// MFMA group, A from LDS
#define MFMA_ITER(AB, BB, ACC)                                                      \
    {                                                                               \
        _Pragma("unroll")                                                           \
        for (int ks = 0; ks < 2; ks++) {                                            \
            const int qx = (((ks * 4 + quad) ^ r7) * 8);                            \
            bf16x8 a0 = *(const bf16x8*)&(AB)[(wv * 32 + lm) * 64 + qx];            \
            bf16x8 a1 = *(const bf16x8*)&(AB)[(wv * 32 + 16 + lm) * 64 + qx];       \
            _Pragma("unroll")                                                       \
            for (int ct = 0; ct < 8; ct++) {                                        \
                bf16x8 b = *(const bf16x8*)&(BB)[(ct * 16 + lm) * 64 + qx];         \
                ACC[0][ct] = __builtin_amdgcn_mfma_f32_16x16x32_bf16(b, a0, ACC[0][ct], 0, 0, 0); \
                ACC[1][ct] = __builtin_amdgcn_mfma_f32_16x16x32_bf16(b, a1, ACC[1][ct], 0, 0, 0); \
            }                                                                       \
        }                                                                           \
    }

// MFMA group, A from registers (AF = bf16x8[4]: rt0ks0,rt0ks1,rt1ks0,rt1ks1)
#define MFMA_RG(BB, AF, ACC, FRESH)                                                 \
    {                                                                               \
        __builtin_amdgcn_s_setprio(1);                                              \
        _Pragma("unroll")                                                           \
        for (int ks = 0; ks < 2; ks++) {                                            \
            const int qx = ((ks * 4 + quad) ^ r7) * 8;                              \
            _Pragma("unroll")                                                       \
            for (int ct = 0; ct < 8; ct++) {                                        \
                bf16x8 b = *(const bf16x8*)&(BB)[(ct * 16 + lm) * 64 + qx];         \
                f32x4 c0 = ((FRESH) && ks == 0) ? (f32x4){0.f, 0.f, 0.f, 0.f} : ACC[0][ct]; \
                f32x4 c1 = ((FRESH) && ks == 0) ? (f32x4){0.f, 0.f, 0.f, 0.f} : ACC[1][ct]; \
                ACC[0][ct] = __builtin_amdgcn_mfma_f32_16x16x32_bf16(b, (AF)[ks], c0, 0, 0, 0); \
                ACC[1][ct] = __builtin_amdgcn_mfma_f32_16x16x32_bf16(b, (AF)[2 + ks], c1, 0, 0, 0); \
            }                                                                       \
        }                                                                           \
        __builtin_amdgcn_s_setprio(0);                                              \
    }

#define FOLD(SRC, S0, S1)                                                           \
    _Pragma("unroll")                                                               \
    for (int ct = 0; ct < 8; ct++) {                                                \
        mI[0][ct] += (S0) * SRC[0][ct];                                             \
        mI[1][ct] += (S1) * SRC[1][ct];                                             \
    }

// ---------------------------------------------------------------- PQ = h @ [Wtop | Wbot] (+bias on Q)
__global__ __launch_bounds__(256, 2) void gemm_pq_kernel(
    const short* __restrict__ hbf, const short* __restrict__ wpreT2,
    const float* __restrict__ bpre, short* __restrict__ PQ)
{
    __shared__ __align__(16) short As[2][8192];
    __shared__ __align__(16) short Bs[2][8192];

    const int tid = threadIdx.x;
    const int cg = blockIdx.x & 1;            // 0 = P cols, 1 = Q cols
    const int bn = (blockIdx.x >> 1) * 128;
    const int lane = tid & 63, wv = tid >> 6;
    const int lm = lane & 15, quad = lane >> 4;
    const int r7 = lm & 7;
    const short* Bsrc = wpreT2 + cg * 128 * 128;   // this block's 128 weight rows, [n][k=128]

    f32x4 acc[2][8];
#pragma unroll
    for (int a = 0; a < 2; a++)
#pragma unroll
        for (int b = 0; b < 8; b++) acc[a][b] = (f32x4){0.f, 0.f, 0.f, 0.f};

    // issue k0 (8) then k1 (8) -> 16 in flight
    stageA_t(As[0], hbf, 128, 0, bn, wv, lane);
    stageB_t(Bs[0], Bsrc, 128, 0, wv, lane);
    stageA_t(As[1], hbf, 128, 64, bn, wv, lane);
    stageB_t(Bs[1], Bsrc, 128, 64, wv, lane);
    WAIT_BAR(8);                       // k0 landed (all waves)
    MFMA_ITER(As[0], Bs[0], acc);
    WAIT_BAR(0);                       // k1 landed
    MFMA_ITER(As[1], Bs[1], acc);

#pragma unroll
    for (int rt = 0; rt < 2; rt++) {
        int row = wv * 32 + rt * 16 + lm;
        int n = bn + row;
        if (n >= N_NODES) continue;
        short* dst = PQ + (long)n * 256;
#pragma unroll
        for (int ct = 0; ct < 8; ct++) {
            int col = cg * 128 + ct * 16 + quad * 4;
            float v0 = acc[rt][ct][0], v1 = acc[rt][ct][1], v2 = acc[rt][ct][2], v3 = acc[rt][ct][3];
            if (cg) {
                float4 bv = *(const float4*)(bpre + (col - 128));
                v0 += bv.x; v1 += bv.y; v2 += bv.z; v3 += bv.w;
            }
            int2 pkd; pkd.x = (int)pk2(v0, v1); pkd.y = (int)pk2(v2, v3);
            *(int2*)(dst + col) = pkd;
        }
    }
}

// ---------------------------------------------------------------- fused edge compute + stats: one wave per node
__global__ __launch_bounds__(256) void edgestats_kernel(
    const short* __restrict__ PQ, const int* __restrict__ srcs,
    const int* __restrict__ off, const int* __restrict__ degc, short* __restrict__ aggbf)
{
    const int wv = threadIdx.x >> 6, lane = threadIdx.x & 63;
    const int n = blockIdx.x * 4 + wv;            // grid 12500 * 4 waves = 50000
    const unsigned* Pb = (const unsigned*)PQ;     // u32 view: row = 128 u32 (P=0..63, Q=64..127)

    const int s0 = __builtin_amdgcn_readfirstlane(off[n]);
    const int s1 = s0 + __builtin_amdgcn_readfirstlane(degc[n]);

    unsigned qu = Pb[(long)n * 128 + 64 + lane];
    const float qa = blo(qu), qb = bhi(qu);

    float sA = 0.f, sB = 0.f, qA = 0.f, qB = 0.f;
    float mxA = -1e30f, mxB = -1e30f, mnA = 1e30f, mnB = 1e30f;

    int p = s0;
    for (; p + 8 <= s1; p += 8) {
        int idx[8];
#pragma unroll
        for (int j = 0; j < 8; j++) idx[j] = srcs[p + j];
        unsigned u[8];
#pragma unroll
        for (int j = 0; j < 8; j++) u[j] = Pb[(long)idx[j] * 128 + lane];
#pragma unroll
        for (int j = 0; j < 8; j++) {
            float a = blo(u[j]) + qa; a = a > 0.f ? a : 0.f;
            float b = bhi(u[j]) + qb; b = b > 0.f ? b : 0.f;
            sA += a; sB += b; qA += a * a; qB += b * b;
            mxA = fmaxf(mxA, a); mxB = fmaxf(mxB, b);
            mnA = fminf(mnA, a); mnB = fminf(mnB, b);
        }
    }
    if (p + 4 <= s1) {
        int idx[4];
#pragma unroll
        for (int j = 0; j < 4; j++) idx[j] = srcs[p + j];
        unsigned u[4];
#pragma unroll
        for (int j = 0; j < 4; j++) u[j] = Pb[(long)idx[j] * 128 + lane];
#pragma unroll
        for (int j = 0; j < 4; j++) {
            float a = blo(u[j]) + qa; a = a > 0.f ? a : 0.f;
            float b = bhi(u[j]) + qb; b = b > 0.f ? b : 0.f;
            sA += a; sB += b; qA += a * a; qB += b * b;
            mxA = fmaxf(mxA, a); mxB = fmaxf(mxB, b);
            mnA = fminf(mnA, a); mnB = fminf(mnB, b);
        }
        p += 4;
    }
    for (; p < s1; p++) {
        unsigned u = Pb[(long)srcs[p] * 128 + lane];
        float a = blo(u) + qa; a = a > 0.f ? a : 0.f;
        float b = bhi(u) + qb; b = b > 0.f ? b : 0.f;
        sA += a; sB += b; qA += a * a; qB += b * b;
        mxA = fmaxf(mxA, a); mxB = fmaxf(mxB, b);
        mnA = fminf(mnA, a); mnB = fminf(mnB, b);
    }

    float inv = 1.0f / (float)(s1 - s0);   // deg >= 1 guaranteed (self-loops)
    float mA = sA * inv, mB = sB * inv;
    float vA = qA * inv - mA * mA; vA = vA > 0.f ? vA : 0.f;
    float vB = qB * inv - mB * mB; vB = vB > 0.f ? vB : 0.f;
    float stA = sqrtf(vA + EPS_V), stB = sqrtf(vB + EPS_V);

    unsigned* ag = (unsigned*)(aggbf + (long)n * 512);
    ag[lane]       = pk2(mA, mB);
    ag[64 + lane]  = pk2(mxA, mxB);
    ag[128 + lane] = pk2(mnA, mnB);
    ag[192 + lane] = pk2(stA, stB);
}

// ---------------------------------------------------------------- fused post + mix per node
// v9 = proven v7 (43.8us) + single As buffer (agg tile consumed by s0 reg-hoist before
// s1 stages the next -> double-buffer unnecessary). LDS 65->49 KB => 3 blocks/CU.
// Mix phase: 2-pass through the single As with wave-private rows + lgkm fences
// (pattern correctness-proven in r9). Ledger identical to v7 at every wait.
__global__ __launch_bounds__(256, 3) void node_kernel(
    const float* __restrict__ h, const short* __restrict__ hbf, const short* __restrict__ aggbf,
    const int* __restrict__ degc, const short* __restrict__ wpostT, const float* __restrict__ bpost,
    const short* __restrict__ wmixT, const float* __restrict__ bmix, float* __restrict__ out)
{
    __shared__ __align__(16) short As[8192];      // 16 KB: agg staging / hp staging
    __shared__ __align__(16) short Bs[2][8192];   // 32 KB weight double-buffer
    __shared__ float sAmp[128], sAtt[128];

    const int tid = threadIdx.x;
    const int bn = blockIdx.x * 128;
    const int lane = tid & 63, wv = tid >> 6;
    const int lm = lane & 15, quad = lane >> 4;
    const int r7 = lm & 7;

    if (tid < 128) {
        int n = bn + tid; if (n >= N_NODES) n = N_NODES - 1;
        float d = (float)degc[n];
        float ld = logf(d + 1.0f);
        sAmp[tid] = ld * (1.0f / AVG_D_LOG);
        sAtt[tid] = AVG_D_LOG / ld;
    }
    __syncthreads();   // drains degc load -> vmcnt baseline 0 for exact counted waits

    const float am0 = sAmp[wv * 32 + lm],      at0 = sAtt[wv * 32 + lm];
    const float am1 = sAmp[wv * 32 + 16 + lm], at1 = sAtt[wv * 32 + 16 + lm];

    f32x4 mI[2][8];   // master accumulator (FRESH at P0)

    // prologue FIFO: Bc0(4 lds), h0-frags(4 reg), h1-frags(4 reg), agg0(4 lds) -> 16
    bf16x8 hA0[4], hA1[4];
    stageB_t(Bs[0], wpostT, 1664, 0, wv, lane);
    SB0();
    loadAfr(hA0, hbf, 128, 0, bn, wv, lm, quad);
    loadAfr(hA1, hbf, 128, 64, bn, wv, lm, quad);
    SB0();
    stageA_t(As, aggbf, 512, 0, bn, wv, lane);         // agg0 -> As

    // P0: wait Bc0 (oldest 4; hA0 regs auto-waited by compiler); stage Bc1; MFMA h0 x c0
    WAIT_BAR(12);
    stageB_t(Bs[1], wpostT, 1664, 64, wv, lane);
    MFMA_RG(Bs[0], hA0, mI, 1);

    // P1: drain all (Bc1 + hA1 + agg0); stage Bid0 -> Bs[0]; MFMA h1 x c1
    WAIT_BAR(0);
    stageB_t(Bs[0], wpostT, 1664, 2 * 64, wv, lane);
    MFMA_RG(Bs[1], hA1, mI, 0);

    // j-loop: s0 (id_j), s1 (amp_j), s2 (att_j); 1 barrier/phase; agg via single As.
    for (int j = 0; j < 8; j++) {
        const int pb = j & 1, pn = pb ^ 1;
        bf16x8 aR[4];

        // s0: wait 0 (Bid_j + agg_j landed); stage Bamp_j -> Bs[pn]; hoist aR; MFMA id
        WAIT_BAR(0);
        stageB_t(Bs[pn], wpostT, 1664, (10 + j) * 64, wv, lane);
#pragma unroll
        for (int rt = 0; rt < 2; rt++)
#pragma unroll
            for (int ks = 0; ks < 2; ks++)
                aR[rt * 2 + ks] = *(const bf16x8*)&As[(wv * 32 + rt * 16 + lm) * 64 + ((ks * 4 + quad) ^ r7) * 8];
        MFMA_RG(Bs[pb], aR, mI, 0);

        // s1: wait 0 (Bamp landed); stage Batt_j -> Bs[pb] then agg_{j+1} -> As
        //     (safe: all waves' s0 hoists lgkm-complete before this barrier); MFMA amp; fold
        WAIT_BAR(0);
        stageB_t(Bs[pb], wpostT, 1664, (18 + j) * 64, wv, lane);
        SB0();
        if (j < 7) {
            int jn = j + 1;
            stageA_t(As, aggbf, 512, (jn >> 1) * 128 + (jn & 1) * 64, bn, wv, lane);
        }
        {
            f32x4 tp[2][8];
            MFMA_RG(Bs[pn], aR, tp, 1);
            FOLD(tp, am0, am1);
        }

        // s2: wait 4 (lands Batt, preserves agg_{j+1}) [j=7: wait 0];
        //     stage Bid_{j+1} -> Bs[pn] (j=7: Bmix0 -> Bs[0]); MFMA att; fold
        if (j < 7) { WAIT_BAR(4); } else { WAIT_BAR(0); }
        if (j < 7) stageB_t(Bs[pn], wpostT, 1664, (3 + j) * 64, wv, lane);
        else       stageB_t(Bs[pn], wmixT, 128, 0, wv, lane);     // pn=0 at j=7 -> Bmix0 -> Bs[0]
        {
            f32x4 tp[2][8];
            MFMA_RG(Bs[pb], aR, tp, 1);
            FOLD(tp, at0, at1);
        }
    }
    // Bmix0 in flight -> Bs[0]

    // tail: protect Bs[1] (att7 reads done at barrier), stage Bmix1 -> Bs[1]
    BAR_ONLY();
    stageB_t(Bs[1], wmixT, 128, 64, wv, lane);

    // hp = relu(mI + bpost) in place
#pragma unroll
    for (int rt = 0; rt < 2; rt++)
#pragma unroll
        for (int ct = 0; ct < 8; ct++) {
            float4 bv = *(const float4*)(bpost + ct * 16 + quad * 4);
            mI[rt][ct][0] = fmaxf(mI[rt][ct][0] + bv.x, 0.f);
            mI[rt][ct][1] = fmaxf(mI[rt][ct][1] + bv.y, 0.f);
            mI[rt][ct][2] = fmaxf(mI[rt][ct][2] + bv.z, 0.f);
            mI[rt][ct][3] = fmaxf(mI[rt][ct][3] + bv.w, 0.f);
        }

    // mix kc=0: write hp cols 0-63 (swizzled) -> As (own rows only)
#pragma unroll
    for (int rt = 0; rt < 2; rt++) {
        const int row = wv * 32 + rt * 16 + lm;
#pragma unroll
        for (int ct = 0; ct < 4; ct++) {
            int2 pkd; pkd.x = (int)pk2(mI[rt][ct][0], mI[rt][ct][1]);
            pkd.y = (int)pk2(mI[rt][ct][2], mI[rt][ct][3]);
            const int cb = ct * 32 + quad * 8;
            const int sb = ((((cb >> 4) ^ r7) << 4) | (cb & 15));
            *(int2*)((char*)As + row * 128 + sb) = pkd;
        }
    }
    __syncthreads();   // full drain: Bmix vmcnt + hp lgkm; all waves' stages visible

    f32x4 accO[2][8];
#pragma unroll
    for (int a = 0; a < 2; a++)
#pragma unroll
        for (int b = 0; b < 8; b++) accO[a][b] = (f32x4){0.f, 0.f, 0.f, 0.f};
    MFMA_ITER(As, Bs[0], accO);

    // mix kc=1: As rows are wave-private; order reads->writes->reads via lgkm
    LGKM0();
#pragma unroll
    for (int rt = 0; rt < 2; rt++) {
        const int row = wv * 32 + rt * 16 + lm;
#pragma unroll
        for (int ct = 4; ct < 8; ct++) {
            int2 pkd; pkd.x = (int)pk2(mI[rt][ct][0], mI[rt][ct][1]);
            pkd.y = (int)pk2(mI[rt][ct][2], mI[rt][ct][3]);
            const int cb = (ct - 4) * 32 + quad * 8;
            const int sb = ((((cb >> 4) ^ r7) << 4) | (cb & 15));
            *(int2*)((char*)As + row * 128 + sb) = pkd;
        }
    }
    LGKM0();
    MFMA_ITER(As, Bs[1], accO);

    // epilogue: out = h + leaky_relu(accO + b_mix)
#pragma unroll
    for (int rt = 0; rt < 2; rt++) {
        int row = wv * 32 + rt * 16 + lm;
        int n = bn + row;
        if (n >= N_NODES) continue;
#pragma unroll
        for (int ct = 0; ct < 8; ct++) {
            int col = ct * 16 + quad * 4;
            float4 bv = *(const float4*)(bmix + col);
            float4 hv = *(const float4*)(h + (long)n * 128 + col);
            float4 o;
            float v0 = accO[rt][ct][0] + bv.x; v0 = v0 > 0.f ? v0 : 0.01f * v0; o.x = hv.x + v0;
            float v1 = accO[rt][ct][1] + bv.y; v1 = v1 > 0.f ? v1 : 0.01f * v1; o.y = hv.y + v1;
            float v2 = accO[rt][ct][2] + bv.z; v2 = v2 > 0.f ? v2 : 0.01f * v2; o.z = hv.z + v2;
            float v3 = accO[rt][ct][3] + bv.w; v3 = v3 > 0.f ? v3 : 0.01f * v3; o.w = hv.w + v3;
            *(float4*)(out + (long)n * 128 + col) = o;
        }
    }
}

extern "C" void kernel_launch(void* const* d_in, const int* in_sizes, int n_in,
                              void* d_out, int out_size, void* d_ws, size_t ws_size,
                              hipStream_t stream) {
    const float* h     = (const float*)d_in[0];
    const int*   esrc  = (const int*)d_in[1];
    const int*   edst  = (const int*)d_in[2];
    const float* Wpre  = (const float*)d_in[3];
    const float* bpre  = (const float*)d_in[4];
    const float* Wpost = (const float*)d_in[5];
    const float* bpost = (const float*)d_in[6];
    const float* Wmix  = (const float*)d_in[7];
    const float* bmix  = (const float*)d_in[8];
    float* out = (float*)d_out;
    char* ws = (char*)d_ws;

    short* PQ     = (short*)(ws + PQ_B);
    short* aggbf  = (short*)(ws + AGG_B);
    short* hbf    = (short*)(ws + HBF_B);
    short* wpreT2 = (short*)(ws + WPRET2_B);
    short* wpostT = (short*)(ws + WPOSTT_B);
    short* wmixT  = (short*)(ws + WMIXT_B);
    int*   degc   = (int*)(ws + DEGC_B);
    int*   off    = (int*)(ws + OFF_B);
    int*   cursor = (int*)(ws + CUR_B);
    int*   srcs   = (int*)(ws + SRCS_B);
    int*   gcnt   = (int*)(ws + GCNT_B);

    prep_kernel<<<PREP_BLOCKS, 256, 0, stream>>>(h, Wpre, Wpost, Wmix, hbf, wpreT2, wpostT, wmixT, degc, cursor, gcnt);
    hist_kernel<<<(N_EDGES + 255) / 256, 256, 0, stream>>>(edst, degc);
    alloc_kernel<<<(N_NODES + 255) / 256, 256, 0, stream>>>(degc, off, gcnt);
    scatter_kernel<<<(N_EDGES + 255) / 256, 256, 0, stream>>>(esrc, edst, off, cursor, srcs);
    gemm_pq_kernel<<<((N_NODES + 127) / 128) * 2, 256, 0, stream>>>(hbf, wpreT2, bpre, PQ);
    edgestats_kernel<<<N_NODES / 4, 256, 0, stream>>>(PQ, srcs, off, degc, aggbf);
    node_kernel<<<(N_NODES + 127) / 128, 256, 0, stream>>>(h, hbf, aggbf, degc, wpostT, bpost, wmixT, bmix, out);
}

// Round 11
// 244.798 us; speedup vs baseline: 1.2836x; 1.1914x over previous
//
#include <hip/hip_runtime.h>
#include <hip/hip_bf16.h>

#define N_NODES 50000
#define N_EDGES 600000
#define D 128

constexpr float AVG_D_LOG = 1.6094379124341003f;  // log(5)
constexpr float EPS_V = 1e-5f;

// ---- workspace byte offsets (total ~93.1 MB)
#define PQ_B     0ul           // bf16 [50000][256]  P|Q rows     = 25,600,000
#define AGG_B    25600000ul    // bf16 [50000][512]  mean|max|min|std = 51,200,000
#define HBF_B    76800000ul    // bf16 [50000][128]
#define WPRET2_B 89600000ul    // bf16 [256][128]   (P cols | Q cols, [n][k])
#define WPOSTT_B 89665536ul    // bf16 [128][1664]
#define WMIXT_B  90091520ul    // bf16 [128][128]
#define DEGC_B   90124288ul    // int  [50000]
#define OFF_B    90324288ul    // int  [50016]
#define CUR_B    90524352ul    // int  [50000]
#define SRCS_B   90724352ul    // int  [600000]  src ids in dst-sorted order
#define GCNT_B   93124352ul    // int  [1]  global range allocator

typedef __attribute__((ext_vector_type(8))) short bf16x8;
typedef __attribute__((ext_vector_type(4))) float f32x4;

__device__ __forceinline__ short f2b(float f) {
    unsigned u = __builtin_bit_cast(unsigned, f);
    u += 0x7fffu + ((u >> 16) & 1u);   // RNE
    return (short)(u >> 16);
}
__device__ __forceinline__ unsigned pk2(float a, float b) {
    return (unsigned)(unsigned short)f2b(a) | ((unsigned)(unsigned short)f2b(b) << 16);
}
__device__ __forceinline__ float blo(unsigned u) { return __uint_as_float(u << 16); }
__device__ __forceinline__ float bhi(unsigned u) { return __uint_as_float(u & 0xffff0000u); }

// async global->LDS, 16B per lane; LDS dest = wave-uniform base + lane*16
__device__ __forceinline__ void gld_lds16(const void* g, void* l) {
    __builtin_amdgcn_global_load_lds(
        (const __attribute__((address_space(1))) void*)g,
        (__attribute__((address_space(3))) void*)l, 16, 0, 0);
}

// counted-vmcnt barrier pair (T4)
#define WAIT_BAR(N) do {                                              \
    asm volatile("s_waitcnt vmcnt(" #N ")" ::: "memory");             \
    __builtin_amdgcn_sched_barrier(0);                                \
    __builtin_amdgcn_s_barrier();                                     \
    __builtin_amdgcn_sched_barrier(0);                                \
} while (0)
#define BAR_ONLY() do {                                               \
    __builtin_amdgcn_sched_barrier(0);                                \
    __builtin_amdgcn_s_barrier();                                     \
    __builtin_amdgcn_sched_barrier(0);                                \
} while (0)
#define SB0() __builtin_amdgcn_sched_barrier(0)
#define LGKM0() do { asm volatile("s_waitcnt lgkmcnt(0)" ::: "memory"); SB0(); } while (0)

// ---------------------------------------------------------------- prep (8-wide vectorized h conversion)
__global__ __launch_bounds__(256) void prep_kernel(
    const float* __restrict__ h, const float* __restrict__ Wpre,
    const float* __restrict__ Wpost, const float* __restrict__ Wmix,
    short* __restrict__ hbf, short* __restrict__ wpreT2,
    short* __restrict__ wpostT, short* __restrict__ wmixT,
    int* __restrict__ degc, int* __restrict__ cursor, int* __restrict__ gcnt)
{
    long i = (long)blockIdx.x * 256 + threadIdx.x;
    if (i < 800000) {   // 6.4M elements, 8 per thread
        float4 a = *(const float4*)(h + i * 8);
        float4 b = *(const float4*)(h + i * 8 + 4);
        int4 v;
        v.x = (int)pk2(a.x, a.y); v.y = (int)pk2(a.z, a.w);
        v.z = (int)pk2(b.x, b.y); v.w = (int)pk2(b.z, b.w);
        *(int4*)(hbf + i * 8) = v;
        return;
    }
    i -= 800000;
    if (i < 32768) {  // wpreT2[n][k]: n<128 -> Wpre[k][n] (top); n>=128 -> Wpre[k+128][n-128]
        int n = i >> 7, k = i & 127;
        float v = (n < 128) ? Wpre[k * 128 + n] : Wpre[(k + 128) * 128 + (n - 128)];
        wpreT2[n * 128 + k] = f2b(v);
        return;
    }
    i -= 32768;
    if (i < 212992) { int k = i >> 7, n = i & 127; wpostT[n * 1664 + k] = f2b(Wpost[k * 128 + n]); return; }
    i -= 212992;
    if (i < 16384) { int k = i >> 7, n = i & 127; wmixT[n * 128 + k] = f2b(Wmix[k * 128 + n]); return; }
    i -= 16384;
    if (i < N_NODES) { degc[i] = 0; return; }
    i -= N_NODES;
    if (i < N_NODES) { cursor[i] = 0; return; }
    i -= N_NODES;
    if (i == 0) *gcnt = 0;
}
#define PREP_BLOCKS ((800000 + 32768 + 212992 + 16384 + 2 * N_NODES + 1 + 255) / 256)

// ---------------------------------------------------------------- degree histogram
__global__ __launch_bounds__(256) void hist_kernel(const int* __restrict__ edst, int* __restrict__ degc) {
    int e = blockIdx.x * 256 + threadIdx.x;
    if (e < N_EDGES) atomicAdd(&degc[edst[e]], 1);
}

// ---------------------------------------------------------------- range alloc (replaces 3-kernel scan)
__global__ __launch_bounds__(256) void alloc_kernel(const int* __restrict__ degc,
                                                    int* __restrict__ off, int* __restrict__ gcnt) {
    int n = blockIdx.x * 256 + threadIdx.x;
    int d = (n < N_NODES) ? degc[n] : 0;
    int pre = d;
#pragma unroll
    for (int o = 1; o < 64; o <<= 1) {
        int t = __shfl_up(pre, o);
        if ((threadIdx.x & 63) >= o) pre += t;
    }
    int base = 0;
    if ((threadIdx.x & 63) == 63) base = atomicAdd(gcnt, pre);   // pre = wave total at lane 63
    base = __shfl(base, 63);
    if (n < N_NODES) off[n] = base + pre - d;                    // exclusive within wave
}

// ---------------------------------------------------------------- scatter srcs into dst-sorted order
__global__ __launch_bounds__(256) void scatter_kernel(const int* __restrict__ esrc, const int* __restrict__ edst,
                                                      const int* __restrict__ off, int* __restrict__ cursor,
                                                      int* __restrict__ srcs) {
    int e = blockIdx.x * 256 + threadIdx.x;
    if (e < N_EDGES) {
        int d = edst[e];
        int p = off[d] + atomicAdd(&cursor[d], 1);
        srcs[p] = esrc[e];
    }
}

// ---------------------------------------------------------------- shared GEMM stage/compute helpers
// stage one 128x64 A tile (node rows): 4 gld_lds per wave (256-thread block)
__device__ __forceinline__ void stageA_t(short* ldsT, const short* src, int rs, int co,
                                         int bn, int wv, int lane) {
    const int sub = lane >> 3, seg = lane & 7;
    const int sg = (seg ^ sub) * 8;          // pre-swizzled global seg (row&7 == sub)
#pragma unroll
    for (int t = 0; t < 4; t++) {
        int i = wv * 4 + t;
        int row = i * 8 + sub;
        int n = bn + row; if (n >= N_NODES) n = N_NODES - 1;
        gld_lds16(src + (long)n * rs + co + sg, ldsT + i * 512);
    }
}
// stage one 128x64 B tile (weight rows, no clamp)
__device__ __forceinline__ void stageB_t(short* ldsT, const short* src, int rs, int co,
                                         int wv, int lane) {
    const int sub = lane >> 3, seg = lane & 7;
    const int sg = (seg ^ sub) * 8;
#pragma unroll
    for (int t = 0; t < 4; t++) {
        int i = wv * 4 + t;
        int row = i * 8 + sub;
        gld_lds16(src + (long)row * rs + co + sg, ldsT + i * 512);
    }
}
// load 4 A-fragments (rt x ks) for this wave's 32 rows, K=64 chunk at co, direct global->reg
__device__ __forceinline__ void loadAfr(bf16x8* a, const short* src, int rs, int co,
                                        int bn, int wv, int lm, int quad) {
#pragma unroll
    for (int rt = 0; rt < 2; rt++)
#pragma unroll
        for (int ks = 0; ks < 2; ks++) {
            int n = bn + wv * 32 + rt * 16 + lm; if (n >= N_NODES) n = N_NODES - 1;
            a[rt * 2 + ks] = *(const bf16x8*)(src + (long)n * rs + co + ks * 32 + quad * 8);
        }
}

// MFMA group, A from LDS
#define MFMA_ITER(AB, BB, ACC)                                                      \
    {                                                                               \
        _Pragma("unroll")                                                           \
        for (int ks = 0; ks < 2; ks++) {                                            \
            const int qx = (((ks * 4 + quad) ^ r7) * 8);                            \
            bf16x8 a0 = *(const bf16x8*)&(AB)[(wv * 32 + lm) * 64 + qx];            \
            bf16x8 a1 = *(const bf16x8*)&(AB)[(wv * 32 + 16 + lm) * 64 + qx];       \
            _Pragma("unroll")                                                       \
            for (int ct = 0; ct < 8; ct++) {                                        \
                bf16x8 b = *(const bf16x8*)&(BB)[(ct * 16 + lm) * 64 + qx];         \
                ACC[0][ct] = __builtin_amdgcn_mfma_f32_16x16x32_bf16(b, a0, ACC[0][ct], 0, 0, 0); \
                ACC[1][ct] = __builtin_amdgcn_mfma_f32_16x16x32_bf16(b, a1, ACC[1][ct], 0, 0, 0); \
            }                                                                       \
        }                                                                           \
    }

// MFMA group, A from registers (AF = bf16x8[4]: rt0ks0,rt0ks1,rt1ks0,rt1ks1)
#define MFMA_RG(BB, AF, ACC, FRESH)                                                 \
    {                                                                               \
        __builtin_amdgcn_s_setprio(1);                                              \
        _Pragma("unroll")                                                           \
        for (int ks = 0; ks < 2; ks++) {                                            \
            const int qx = ((ks * 4 + quad) ^ r7) * 8;                              \
            _Pragma("unroll")                                                       \
            for (int ct = 0; ct < 8; ct++) {                                        \
                bf16x8 b = *(const bf16x8*)&(BB)[(ct * 16 + lm) * 64 + qx];         \
                f32x4 c0 = ((FRESH) && ks == 0) ? (f32x4){0.f, 0.f, 0.f, 0.f} : ACC[0][ct]; \
                f32x4 c1 = ((FRESH) && ks == 0) ? (f32x4){0.f, 0.f, 0.f, 0.f} : ACC[1][ct]; \
                ACC[0][ct] = __builtin_amdgcn_mfma_f32_16x16x32_bf16(b, (AF)[ks], c0, 0, 0, 0); \
                ACC[1][ct] = __builtin_amdgcn_mfma_f32_16x16x32_bf16(b, (AF)[2 + ks], c1, 0, 0, 0); \
            }                                                                       \
        }                                                                           \
        __builtin_amdgcn_s_setprio(0);                                              \
    }

#define FOLD(SRC, S0, S1)                                                           \
    _Pragma("unroll")                                                               \
    for (int ct = 0; ct < 8; ct++) {                                                \
        mI[0][ct] += (S0) * SRC[0][ct];                                             \
        mI[1][ct] += (S1) * SRC[1][ct];                                             \
    }

// ---------------------------------------------------------------- PQ = h @ [Wtop | Wbot] (+bias on Q)
__global__ __launch_bounds__(256, 2) void gemm_pq_kernel(
    const short* __restrict__ hbf, const short* __restrict__ wpreT2,
    const float* __restrict__ bpre, short* __restrict__ PQ)
{
    __shared__ __align__(16) short As[2][8192];
    __shared__ __align__(16) short Bs[2][8192];

    const int tid = threadIdx.x;
    const int cg = blockIdx.x & 1;            // 0 = P cols, 1 = Q cols
    const int bn = (blockIdx.x >> 1) * 128;
    const int lane = tid & 63, wv = tid >> 6;
    const int lm = lane & 15, quad = lane >> 4;
    const int r7 = lm & 7;
    const short* Bsrc = wpreT2 + cg * 128 * 128;   // this block's 128 weight rows, [n][k=128]

    f32x4 acc[2][8];
#pragma unroll
    for (int a = 0; a < 2; a++)
#pragma unroll
        for (int b = 0; b < 8; b++) acc[a][b] = (f32x4){0.f, 0.f, 0.f, 0.f};

    // issue k0 (8) then k1 (8) -> 16 in flight
    stageA_t(As[0], hbf, 128, 0, bn, wv, lane);
    stageB_t(Bs[0], Bsrc, 128, 0, wv, lane);
    stageA_t(As[1], hbf, 128, 64, bn, wv, lane);
    stageB_t(Bs[1], Bsrc, 128, 64, wv, lane);
    WAIT_BAR(8);                       // k0 landed (all waves)
    MFMA_ITER(As[0], Bs[0], acc);
    WAIT_BAR(0);                       // k1 landed
    MFMA_ITER(As[1], Bs[1], acc);

#pragma unroll
    for (int rt = 0; rt < 2; rt++) {
        int row = wv * 32 + rt * 16 + lm;
        int n = bn + row;
        if (n >= N_NODES) continue;
        short* dst = PQ + (long)n * 256;
#pragma unroll
        for (int ct = 0; ct < 8; ct++) {
            int col = cg * 128 + ct * 16 + quad * 4;
            float v0 = acc[rt][ct][0], v1 = acc[rt][ct][1], v2 = acc[rt][ct][2], v3 = acc[rt][ct][3];
            if (cg) {
                float4 bv = *(const float4*)(bpre + (col - 128));
                v0 += bv.x; v1 += bv.y; v2 += bv.z; v3 += bv.w;
            }
            int2 pkd; pkd.x = (int)pk2(v0, v1); pkd.y = (int)pk2(v2, v3);
            *(int2*)(dst + col) = pkd;
        }
    }
}

// ---------------------------------------------------------------- fused edge compute + stats: one wave per node
__global__ __launch_bounds__(256) void edgestats_kernel(
    const short* __restrict__ PQ, const int* __restrict__ srcs,
    const int* __restrict__ off, const int* __restrict__ degc, short* __restrict__ aggbf)
{
    const int wv = threadIdx.x >> 6, lane = threadIdx.x & 63;
    const int n = blockIdx.x * 4 + wv;            // grid 12500 * 4 waves = 50000
    const unsigned* Pb = (const unsigned*)PQ;     // u32 view: row = 128 u32 (P=0..63, Q=64..127)

    const int s0 = __builtin_amdgcn_readfirstlane(off[n]);
    const int s1 = s0 + __builtin_amdgcn_readfirstlane(degc[n]);

    unsigned qu = Pb[(long)n * 128 + 64 + lane];
    const float qa = blo(qu), qb = bhi(qu);

    float sA = 0.f, sB = 0.f, qA = 0.f, qB = 0.f;
    float mxA = -1e30f, mxB = -1e30f, mnA = 1e30f, mnB = 1e30f;

    int p = s0;
    for (; p + 8 <= s1; p += 8) {
        int idx[8];
#pragma unroll
        for (int j = 0; j < 8; j++) idx[j] = srcs[p + j];
        unsigned u[8];
#pragma unroll
        for (int j = 0; j < 8; j++) u[j] = Pb[(long)idx[j] * 128 + lane];
#pragma unroll
        for (int j = 0; j < 8; j++) {
            float a = blo(u[j]) + qa; a = a > 0.f ? a : 0.f;
            float b = bhi(u[j]) + qb; b = b > 0.f ? b : 0.f;
            sA += a; sB += b; qA += a * a; qB += b * b;
            mxA = fmaxf(mxA, a); mxB = fmaxf(mxB, b);
            mnA = fminf(mnA, a); mnB = fminf(mnB, b);
        }
    }
    if (p + 4 <= s1) {
        int idx[4];
#pragma unroll
        for (int j = 0; j < 4; j++) idx[j] = srcs[p + j];
        unsigned u[4];
#pragma unroll
        for (int j = 0; j < 4; j++) u[j] = Pb[(long)idx[j] * 128 + lane];
#pragma unroll
        for (int j = 0; j < 4; j++) {
            float a = blo(u[j]) + qa; a = a > 0.f ? a : 0.f;
            float b = bhi(u[j]) + qb; b = b > 0.f ? b : 0.f;
            sA += a; sB += b; qA += a * a; qB += b * b;
            mxA = fmaxf(mxA, a); mxB = fmaxf(mxB, b);
            mnA = fminf(mnA, a); mnB = fminf(mnB, b);
        }
        p += 4;
    }
    for (; p < s1; p++) {
        unsigned u = Pb[(long)srcs[p] * 128 + lane];
        float a = blo(u) + qa; a = a > 0.f ? a : 0.f;
        float b = bhi(u) + qb; b = b > 0.f ? b : 0.f;
        sA += a; sB += b; qA += a * a; qB += b * b;
        mxA = fmaxf(mxA, a); mxB = fmaxf(mxB, b);
        mnA = fminf(mnA, a); mnB = fminf(mnB, b);
    }

    float inv = 1.0f / (float)(s1 - s0);   // deg >= 1 guaranteed (self-loops)
    float mA = sA * inv, mB = sB * inv;
    float vA = qA * inv - mA * mA; vA = vA > 0.f ? vA : 0.f;
    float vB = qB * inv - mB * mB; vB = vB > 0.f ? vB : 0.f;
    float stA = sqrtf(vA + EPS_V), stB = sqrtf(vB + EPS_V);

    unsigned* ag = (unsigned*)(aggbf + (long)n * 512);
    ag[lane]       = pk2(mA, mB);
    ag[64 + lane]  = pk2(mxA, mxB);
    ag[128 + lane] = pk2(mnA, mnB);
    ag[192 + lane] = pk2(stA, stB);
}

// ---------------------------------------------------------------- fused post + mix per node
// v10 = v9 structure (single As, 49 KB LDS, hardware-verified in r10) with
// __launch_bounds__(256, 2): r10's (256,3) capped VGPR at 170 and the allocator
// SPILLED (VGPR 84, WRITE_SIZE 63MB). Bound 2 lets it allocate ~116-130 like v7;
// since 130 <= 512/3 = 170, the HW still gives 3 blocks/CU from the 49 KB LDS.
// Worst case (alloc > 170): 2 blocks/CU == round-8's measured 43.8 us. No spill path.
__global__ __launch_bounds__(256, 2) void node_kernel(
    const float* __restrict__ h, const short* __restrict__ hbf, const short* __restrict__ aggbf,
    const int* __restrict__ degc, const short* __restrict__ wpostT, const float* __restrict__ bpost,
    const short* __restrict__ wmixT, const float* __restrict__ bmix, float* __restrict__ out)
{
    __shared__ __align__(16) short As[8192];      // 16 KB: agg staging / hp staging
    __shared__ __align__(16) short Bs[2][8192];   // 32 KB weight double-buffer
    __shared__ float sAmp[128], sAtt[128];

    const int tid = threadIdx.x;
    const int bn = blockIdx.x * 128;
    const int lane = tid & 63, wv = tid >> 6;
    const int lm = lane & 15, quad = lane >> 4;
    const int r7 = lm & 7;

    if (tid < 128) {
        int n = bn + tid; if (n >= N_NODES) n = N_NODES - 1;
        float d = (float)degc[n];
        float ld = logf(d + 1.0f);
        sAmp[tid] = ld * (1.0f / AVG_D_LOG);
        sAtt[tid] = AVG_D_LOG / ld;
    }
    __syncthreads();   // drains degc load -> vmcnt baseline 0 for exact counted waits

    const float am0 = sAmp[wv * 32 + lm],      at0 = sAtt[wv * 32 + lm];
    const float am1 = sAmp[wv * 32 + 16 + lm], at1 = sAtt[wv * 32 + 16 + lm];

    f32x4 mI[2][8];   // master accumulator (FRESH at P0)

    // prologue FIFO: Bc0(4 lds), h0-frags(4 reg), h1-frags(4 reg), agg0(4 lds) -> 16
    bf16x8 hA0[4], hA1[4];
    stageB_t(Bs[0], wpostT, 1664, 0, wv, lane);
    SB0();
    loadAfr(hA0, hbf, 128, 0, bn, wv, lm, quad);
    loadAfr(hA1, hbf, 128, 64, bn, wv, lm, quad);
    SB0();
    stageA_t(As, aggbf, 512, 0, bn, wv, lane);         // agg0 -> As

    // P0: wait Bc0 (oldest 4; hA0 regs auto-waited by compiler); stage Bc1; MFMA h0 x c0
    WAIT_BAR(12);
    stageB_t(Bs[1], wpostT, 1664, 64, wv, lane);
    MFMA_RG(Bs[0], hA0, mI, 1);

    // P1: drain all (Bc1 + hA1 + agg0); stage Bid0 -> Bs[0]; MFMA h1 x c1
    WAIT_BAR(0);
    stageB_t(Bs[0], wpostT, 1664, 2 * 64, wv, lane);
    MFMA_RG(Bs[1], hA1, mI, 0);

    // j-loop: s0 (id_j), s1 (amp_j), s2 (att_j); 1 barrier/phase; agg via single As.
    for (int j = 0; j < 8; j++) {
        const int pb = j & 1, pn = pb ^ 1;
        bf16x8 aR[4];

        // s0: wait 0 (Bid_j + agg_j landed); stage Bamp_j -> Bs[pn]; hoist aR; MFMA id
        WAIT_BAR(0);
        stageB_t(Bs[pn], wpostT, 1664, (10 + j) * 64, wv, lane);
#pragma unroll
        for (int rt = 0; rt < 2; rt++)
#pragma unroll
            for (int ks = 0; ks < 2; ks++)
                aR[rt * 2 + ks] = *(const bf16x8*)&As[(wv * 32 + rt * 16 + lm) * 64 + ((ks * 4 + quad) ^ r7) * 8];
        MFMA_RG(Bs[pb], aR, mI, 0);

        // s1: wait 0 (Bamp landed); stage Batt_j -> Bs[pb] then agg_{j+1} -> As
        //     (safe: all waves' s0 hoists lgkm-complete before this barrier); MFMA amp; fold
        WAIT_BAR(0);
        stageB_t(Bs[pb], wpostT, 1664, (18 + j) * 64, wv, lane);
        SB0();
        if (j < 7) {
            int jn = j + 1;
            stageA_t(As, aggbf, 512, (jn >> 1) * 128 + (jn & 1) * 64, bn, wv, lane);
        }
        {
            f32x4 tp[2][8];
            MFMA_RG(Bs[pn], aR, tp, 1);
            FOLD(tp, am0, am1);
        }

        // s2: wait 4 (lands Batt, preserves agg_{j+1}) [j=7: wait 0];
        //     stage Bid_{j+1} -> Bs[pn] (j=7: Bmix0 -> Bs[0]); MFMA att; fold
        if (j < 7) { WAIT_BAR(4); } else { WAIT_BAR(0); }
        if (j < 7) stageB_t(Bs[pn], wpostT, 1664, (3 + j) * 64, wv, lane);
        else       stageB_t(Bs[pn], wmixT, 128, 0, wv, lane);     // pn=0 at j=7 -> Bmix0 -> Bs[0]
        {
            f32x4 tp[2][8];
            MFMA_RG(Bs[pb], aR, tp, 1);
            FOLD(tp, at0, at1);
        }
    }
    // Bmix0 in flight -> Bs[0]

    // tail: protect Bs[1] (att7 reads done at barrier), stage Bmix1 -> Bs[1]
    BAR_ONLY();
    stageB_t(Bs[1], wmixT, 128, 64, wv, lane);

    // hp = relu(mI + bpost) in place
#pragma unroll
    for (int rt = 0; rt < 2; rt++)
#pragma unroll
        for (int ct = 0; ct < 8; ct++) {
            float4 bv = *(const float4*)(bpost + ct * 16 + quad * 4);
            mI[rt][ct][0] = fmaxf(mI[rt][ct][0] + bv.x, 0.f);
            mI[rt][ct][1] = fmaxf(mI[rt][ct][1] + bv.y, 0.f);
            mI[rt][ct][2] = fmaxf(mI[rt][ct][2] + bv.z, 0.f);
            mI[rt][ct][3] = fmaxf(mI[rt][ct][3] + bv.w, 0.f);
        }

    // mix kc=0: write hp cols 0-63 (swizzled) -> As (own rows only)
#pragma unroll
    for (int rt = 0; rt < 2; rt++) {
        const int row = wv * 32 + rt * 16 + lm;
#pragma unroll
        for (int ct = 0; ct < 4; ct++) {
            int2 pkd; pkd.x = (int)pk2(mI[rt][ct][0], mI[rt][ct][1]);
            pkd.y = (int)pk2(mI[rt][ct][2], mI[rt][ct][3]);
            const int cb = ct * 32 + quad * 8;
            const int sb = ((((cb >> 4) ^ r7) << 4) | (cb & 15));
            *(int2*)((char*)As + row * 128 + sb) = pkd;
        }
    }
    __syncthreads();   // full drain: Bmix vmcnt + hp lgkm; all waves' stages visible

    f32x4 accO[2][8];
#pragma unroll
    for (int a = 0; a < 2; a++)
#pragma unroll
        for (int b = 0; b < 8; b++) accO[a][b] = (f32x4){0.f, 0.f, 0.f, 0.f};
    MFMA_ITER(As, Bs[0], accO);

    // mix kc=1: As rows are wave-private; order reads->writes->reads via lgkm
    LGKM0();
#pragma unroll
    for (int rt = 0; rt < 2; rt++) {
        const int row = wv * 32 + rt * 16 + lm;
#pragma unroll
        for (int ct = 4; ct < 8; ct++) {
            int2 pkd; pkd.x = (int)pk2(mI[rt][ct][0], mI[rt][ct][1]);
            pkd.y = (int)pk2(mI[rt][ct][2], mI[rt][ct][3]);
            const int cb = (ct - 4) * 32 + quad * 8;
            const int sb = ((((cb >> 4) ^ r7) << 4) | (cb & 15));
            *(int2*)((char*)As + row * 128 + sb) = pkd;
        }
    }
    LGKM0();
    MFMA_ITER(As, Bs[1], accO);

    // epilogue: out = h + leaky_relu(accO + b_mix)
#pragma unroll
    for (int rt = 0; rt < 2; rt++) {
        int row = wv * 32 + rt * 16 + lm;
        int n = bn + row;
        if (n >= N_NODES) continue;
#pragma unroll
        for (int ct = 0; ct < 8; ct++) {
            int col = ct * 16 + quad * 4;
            float4 bv = *(const float4*)(bmix + col);
            float4 hv = *(const float4*)(h + (long)n * 128 + col);
            float4 o;
            float v0 = accO[rt][ct][0] + bv.x; v0 = v0 > 0.f ? v0 : 0.01f * v0; o.x = hv.x + v0;
            float v1 = accO[rt][ct][1] + bv.y; v1 = v1 > 0.f ? v1 : 0.01f * v1; o.y = hv.y + v1;
            float v2 = accO[rt][ct][2] + bv.z; v2 = v2 > 0.f ? v2 : 0.01f * v2; o.z = hv.z + v2;
            float v3 = accO[rt][ct][3] + bv.w; v3 = v3 > 0.f ? v3 : 0.01f * v3; o.w = hv.w + v3;
            *(float4*)(out + (long)n * 128 + col) = o;
        }
    }
}

extern "C" void kernel_launch(void* const* d_in, const int* in_sizes, int n_in,
                              void* d_out, int out_size, void* d_ws, size_t ws_size,
                              hipStream_t stream) {
    const float* h     = (const float*)d_in[0];
    const int*   esrc  = (const int*)d_in[1];
    const int*   edst  = (const int*)d_in[2];
    const float* Wpre  = (const float*)d_in[3];
    const float* bpre  = (const float*)d_in[4];
    const float* Wpost = (const float*)d_in[5];
    const float* bpost = (const float*)d_in[6];
    const float* Wmix  = (const float*)d_in[7];
    const float* bmix  = (const float*)d_in[8];
    float* out = (float*)d_out;
    char* ws = (char*)d_ws;

    short* PQ     = (short*)(ws + PQ_B);
    short* aggbf  = (short*)(ws + AGG_B);
    short* hbf    = (short*)(ws + HBF_B);
    short* wpreT2 = (short*)(ws + WPRET2_B);
    short* wpostT = (short*)(ws + WPOSTT_B);
    short* wmixT  = (short*)(ws + WMIXT_B);
    int*   degc   = (int*)(ws + DEGC_B);
    int*   off    = (int*)(ws + OFF_B);
    int*   cursor = (int*)(ws + CUR_B);
    int*   srcs   = (int*)(ws + SRCS_B);
    int*   gcnt   = (int*)(ws + GCNT_B);

    prep_kernel<<<PREP_BLOCKS, 256, 0, stream>>>(h, Wpre, Wpost, Wmix, hbf, wpreT2, wpostT, wmixT, degc, cursor, gcnt);
    hist_kernel<<<(N_EDGES + 255) / 256, 256, 0, stream>>>(edst, degc);
    alloc_kernel<<<(N_NODES + 255) / 256, 256, 0, stream>>>(degc, off, gcnt);
    scatter_kernel<<<(N_EDGES + 255) / 256, 256, 0, stream>>>(esrc, edst, off, cursor, srcs);
    gemm_pq_kernel<<<((N_NODES + 127) / 128) * 2, 256, 0, stream>>>(hbf, wpreT2, bpre, PQ);
    edgestats_kernel<<<N_NODES / 4, 256, 0, stream>>>(PQ, srcs, off, degc, aggbf);
    node_kernel<<<(N_NODES + 127) / 128, 256, 0, stream>>>(h, hbf, aggbf, degc, wpostT, bpost, wmixT, bmix, out);
}